// Round 5
// baseline (713.423 us; speedup 1.0000x reference)
//
#include <hip/hip_runtime.h>
#include <hip/hip_bf16.h>

constexpr int N_NODES = 100000;
constexpr int N_REL   = 4;
constexpr int N_EDGES = 600000;
constexpr int MAXDEG  = 32;          // Poisson(6): P(deg>=32) ~ 7e-14 per node
constexpr int D       = 128;
constexpr int KTOT    = N_REL * D;   // 512 concat output cols of Ybig
constexpr int M_PAD   = 100096;      // 782 blocks * 128 rows

// Bucketed build parameters
constexpr int BKT_SHIFT = 11;                     // node -> bucket
constexpr int NPB       = 1 << BKT_SHIFT;         // 2048 nodes per bucket
constexpr int NBKT      = 64;                     // padded (49 real)
constexpr int NBKT_REAL = (N_NODES + NPB - 1) / NPB;   // 49
constexpr int BCAP      = 28672;                  // entries per (rel,bucket) region (mean 24576, +26 sigma)
constexpr int FLUSH     = 32;                     // flush unit (256B bursts for uint2)
constexpr int PCAP      = 96;                     // LDS staging capacity per bucket
constexpr int EPB       = N_EDGES / 64;           // 9375 edges per partition block

typedef __attribute__((ext_vector_type(8))) short bf16x8;   // MFMA A/B frag (4 VGPRs)
typedef __attribute__((ext_vector_type(4))) float f32x4;    // MFMA C/D frag

static __device__ __forceinline__ unsigned short f2bf(float f) {
    union { float f; unsigned int u; } v; v.f = f;
    unsigned int r = (v.u + 0x7fffu + ((v.u >> 16) & 1u)) >> 16;  // RNE
    return (unsigned short)r;
}

// ---------------------------------------------------------------------------
// 1a) Partition edges by dst bucket. LDS-staged, coalesced 256B flush bursts,
//     one global atomic per flush (not per edge).
// ---------------------------------------------------------------------------
__global__ __launch_bounds__(256) void partition_dst(const int* __restrict__ edges,
                                                     uint2* __restrict__ part,
                                                     int* __restrict__ gcur) {
    __shared__ int   cnt[NBKT];
    __shared__ uint2 buf[NBKT][PCAP];            // 49.2 KB

    const int tid  = threadIdx.x;
    const int lane = tid & 63;
    const int w    = tid >> 6;
    const int rel  = blockIdx.y;
    const int e0   = blockIdx.x * EPB;
    const int e1   = e0 + EPB;

    if (tid < NBKT) cnt[tid] = 0;
    __syncthreads();

    for (int base_e = e0; base_e < e1; base_e += 256) {
        int e = base_e + tid;
        if (e < e1) {
            int s = edges[(size_t)rel * 2 * N_EDGES + e];
            int d = edges[(size_t)rel * 2 * N_EDGES + N_EDGES + e];
            int b = d >> BKT_SHIFT;
            int pos = atomicAdd(&cnt[b], 1);
            if (pos < PCAP) buf[b][pos] = make_uint2((unsigned)s, (unsigned)d);
        }
        __syncthreads();
        // flush full FLUSH-units; wave w owns buckets [w*16, w*16+16)
        for (int b = w * (NBKT / 4); b < (w + 1) * (NBKT / 4); b++) {
            int k  = cnt[b];
            int nf = k & ~(FLUSH - 1);
            if (nf > 0) {
                int gbase = 0;
                if (lane == 0) gbase = atomicAdd(&gcur[rel * NBKT + b], nf);
                gbase = __shfl(gbase, 0);
                size_t obase = (size_t)(rel * NBKT + b) * BCAP + gbase;
                for (int i = lane; i < nf; i += 64)
                    part[obase + i] = buf[b][i];
                int rem = k - nf;                 // < 32, moves don't overlap source
                uint2 t = make_uint2(0, 0);
                if (lane < rem) t = buf[b][nf + lane];
                if (lane < rem) buf[b][lane] = t;
                if (lane == 0) cnt[b] = rem;
            }
        }
        __syncthreads();
    }
    // final flush (any size)
    for (int b = w * (NBKT / 4); b < (w + 1) * (NBKT / 4); b++) {
        int k = cnt[b];
        if (k > 0) {
            int gbase = 0;
            if (lane == 0) gbase = atomicAdd(&gcur[rel * NBKT + b], k);
            gbase = __shfl(gbase, 0);
            size_t obase = (size_t)(rel * NBKT + b) * BCAP + gbase;
            for (int i = lane; i < k; i += 64)
                part[obase + i] = buf[b][i];
        }
    }
}

// ---------------------------------------------------------------------------
// 1b) Partition src values by src bucket (4B payload) — for outdeg histogram.
// ---------------------------------------------------------------------------
__global__ __launch_bounds__(256) void partition_src(const int* __restrict__ edges,
                                                     unsigned* __restrict__ part,
                                                     int* __restrict__ gcur) {
    __shared__ int      cnt[NBKT];
    __shared__ unsigned buf[NBKT][PCAP];         // 24.6 KB

    const int tid  = threadIdx.x;
    const int lane = tid & 63;
    const int w    = tid >> 6;
    const int rel  = blockIdx.y;
    const int e0   = blockIdx.x * EPB;
    const int e1   = e0 + EPB;

    if (tid < NBKT) cnt[tid] = 0;
    __syncthreads();

    for (int base_e = e0; base_e < e1; base_e += 256) {
        int e = base_e + tid;
        if (e < e1) {
            int s = edges[(size_t)rel * 2 * N_EDGES + e];
            int b = s >> BKT_SHIFT;
            int pos = atomicAdd(&cnt[b], 1);
            if (pos < PCAP) buf[b][pos] = (unsigned)s;
        }
        __syncthreads();
        for (int b = w * (NBKT / 4); b < (w + 1) * (NBKT / 4); b++) {
            int k  = cnt[b];
            int nf = k & ~(FLUSH - 1);
            if (nf > 0) {
                int gbase = 0;
                if (lane == 0) gbase = atomicAdd(&gcur[rel * NBKT + b], nf);
                gbase = __shfl(gbase, 0);
                size_t obase = (size_t)(rel * NBKT + b) * BCAP + gbase;
                for (int i = lane; i < nf; i += 64)
                    part[obase + i] = buf[b][i];
                int rem = k - nf;
                unsigned t = 0;
                if (lane < rem) t = buf[b][nf + lane];
                if (lane < rem) buf[b][lane] = t;
                if (lane == 0) cnt[b] = rem;
            }
        }
        __syncthreads();
    }
    for (int b = w * (NBKT / 4); b < (w + 1) * (NBKT / 4); b++) {
        int k = cnt[b];
        if (k > 0) {
            int gbase = 0;
            if (lane == 0) gbase = atomicAdd(&gcur[rel * NBKT + b], k);
            gbase = __shfl(gbase, 0);
            size_t obase = (size_t)(rel * NBKT + b) * BCAP + gbase;
            for (int i = lane; i < k; i += 64)
                part[obase + i] = buf[b][i];
        }
    }
}

// ---------------------------------------------------------------------------
// 2a) ELL build per (bucket, rel): LDS cursors (no global atomics); esrc
//     writes land in a 256KB L2-local window; indeg written coalesced.
// ---------------------------------------------------------------------------
__global__ __launch_bounds__(256) void ell_build(const uint2* __restrict__ part,
                                                 const int* __restrict__ gcur,
                                                 int* __restrict__ esrc,
                                                 int* __restrict__ indeg) {
    __shared__ int cur[NPB];                     // 8 KB
    const int tid = threadIdx.x;
    const int b   = blockIdx.x;
    const int rel = blockIdx.y;
    const int base_node = b << BKT_SHIFT;
    const int n = gcur[rel * NBKT + b];

    for (int i = tid; i < NPB; i += 256) cur[i] = 0;
    __syncthreads();

    const uint2* p = part + (size_t)(rel * NBKT + b) * BCAP;
    for (int i = tid; i < n; i += 256) {
        uint2 e = p[i];
        int d   = (int)e.y;
        int pos = atomicAdd(&cur[d - base_node], 1);
        if (pos < MAXDEG)
            esrc[((size_t)rel * N_NODES + d) * MAXDEG + pos] = (int)e.x;
    }
    __syncthreads();
    for (int i = tid; i < NPB; i += 256) {
        int node = base_node + i;
        if (node < N_NODES) indeg[rel * N_NODES + node] = cur[i];
    }
}

// ---------------------------------------------------------------------------
// 2b) Out-degree histogram per (bucket, rel): LDS bins, coalesced writeback.
// ---------------------------------------------------------------------------
__global__ __launch_bounds__(256) void outdeg_hist(const unsigned* __restrict__ part,
                                                   const int* __restrict__ gcur,
                                                   int* __restrict__ outdeg) {
    __shared__ int hist[NPB];
    const int tid = threadIdx.x;
    const int b   = blockIdx.x;
    const int rel = blockIdx.y;
    const int base_node = b << BKT_SHIFT;
    const int n = gcur[rel * NBKT + b];

    for (int i = tid; i < NPB; i += 256) hist[i] = 0;
    __syncthreads();

    const unsigned* p = part + (size_t)(rel * NBKT + b) * BCAP;
    for (int i = tid; i < n; i += 256)
        atomicAdd(&hist[(int)p[i] - base_node], 1);
    __syncthreads();
    for (int i = tid; i < NPB; i += 256) {
        int node = base_node + i;
        if (node < N_NODES) outdeg[rel * N_NODES + node] = hist[i];
    }
}

// ---------------------------------------------------------------------------
// 3) X -> bf16 cast ; W cast+transpose (B-operand layout)
// ---------------------------------------------------------------------------
__global__ __launch_bounds__(256) void xcast_kernel(const float* __restrict__ X,
                                                    unsigned short* __restrict__ Xb) {
    int t = blockIdx.x * blockDim.x + threadIdx.x;
    if (t >= N_NODES * D / 4) return;
    float4 v = ((const float4*)X)[t];
    union { unsigned short u[4]; uint2 d; } o;
    o.u[0] = f2bf(v.x); o.u[1] = f2bf(v.y); o.u[2] = f2bf(v.z); o.u[3] = f2bf(v.w);
    ((uint2*)Xb)[t] = o.d;
}

__global__ __launch_bounds__(256) void wcast_kernel(const float* __restrict__ W,
                                                    unsigned short* __restrict__ Wt) {
    int t = blockIdx.x * blockDim.x + threadIdx.x;   // 65536 threads
    int r = t >> 14;
    int k = (t >> 7) & 127;
    int n = t & 127;
    Wt[(size_t)(r * D + n) * D + k] = f2bf(W[t]);
}

// ---------------------------------------------------------------------------
// 4) Ybig = bf16( rout_r[i] * (Xb @ W_r) )  via 16x16x32 MFMA.
//    Epilogue stores PERMUTED layout: position p = l15*8 + j holds column
//    j*16 + l15  ->  one contiguous 16B bf16x8 store per fragment row.
// ---------------------------------------------------------------------------
__global__ __launch_bounds__(256) void gemm_mfma(const unsigned short* __restrict__ Xb,
                                                 const unsigned short* __restrict__ Wt,
                                                 const int* __restrict__ outdeg,
                                                 unsigned short* __restrict__ Ybig) {
    int w    = threadIdx.x >> 6;
    int lane = threadIdx.x & 63;
    int l15  = lane & 15;
    int quad = lane >> 4;
    int row0 = blockIdx.x * 128 + w * 32;
    int nb   = blockIdx.y;                      // relation

    f32x4 acc[2][8];
#pragma unroll
    for (int m = 0; m < 2; m++)
#pragma unroll
        for (int j = 0; j < 8; j++) acc[m][j] = (f32x4){0.f, 0.f, 0.f, 0.f};

#pragma unroll
    for (int k0 = 0; k0 < D; k0 += 32) {
        bf16x8 a[2];
#pragma unroll
        for (int m = 0; m < 2; m++)
            a[m] = *(const bf16x8*)(Xb + (size_t)(row0 + m * 16 + l15) * D + k0 + quad * 8);
#pragma unroll
        for (int j = 0; j < 8; j++) {
            bf16x8 b = *(const bf16x8*)(Wt + (size_t)(nb * D + j * 16 + l15) * D + k0 + quad * 8);
            acc[0][j] = __builtin_amdgcn_mfma_f32_16x16x32_bf16(a[0], b, acc[0][j], 0, 0, 0);
            acc[1][j] = __builtin_amdgcn_mfma_f32_16x16x32_bf16(a[1], b, acc[1][j], 0, 0, 0);
        }
    }

    // C/D: value acc[m][j][reg] is (row = quad*4+reg, col = j*16+l15).
    // Store columns permuted so each thread's 8 j-values are contiguous.
#pragma unroll
    for (int m = 0; m < 2; m++)
#pragma unroll
        for (int reg = 0; reg < 4; reg++) {
            int row = row0 + m * 16 + quad * 4 + reg;
            if (row < N_NODES) {
                int od = outdeg[nb * N_NODES + row];
                float sc = rsqrtf((float)(od < 1 ? 1 : od));
                union { unsigned short u[8]; uint4 v; } o;
#pragma unroll
                for (int j = 0; j < 8; j++) o.u[j] = f2bf(acc[m][j][reg] * sc);
                *(uint4*)(Ybig + (size_t)row * KTOT + nb * D + l15 * 8) = o.v;
            }
        }
}

// ---------------------------------------------------------------------------
// 5) Final gather: one wave per dst node. Each lane's dword at position
//    p = 2*lane holds columns (c0, c0+16), c0 = ((2*lane)&7)*16 + (lane>>2).
// ---------------------------------------------------------------------------
__global__ __launch_bounds__(256) void gather_ell(const int* __restrict__ esrc,
                                                  const int* __restrict__ indeg,
                                                  const unsigned int* __restrict__ Y4,
                                                  float* __restrict__ Z) {
    int w    = threadIdx.x >> 6;
    int lane = threadIdx.x & 63;
    int d    = blockIdx.x * 4 + w;
    if (d >= N_NODES) return;

    float2 tot = make_float2(0.f, 0.f);
#pragma unroll
    for (int r = 0; r < N_REL; r++) {
        int ind = indeg[r * N_NODES + d];
        int n = ind > MAXDEG ? MAXDEG : ind;
        int s_l = 0;
        if (lane < n)
            s_l = esrc[((size_t)r * N_NODES + d) * MAXDEG + lane];
        float2 acc = make_float2(0.f, 0.f);
        for (int i = 0; i < n; i++) {
            int s = __shfl(s_l, i);
            unsigned int v = Y4[(size_t)s * (KTOT / 2) + r * (D / 2) + lane];
            union { unsigned int u; float f; } lo, hi;
            lo.u = v << 16;
            hi.u = v & 0xFFFF0000u;
            acc.x += lo.f;
            acc.y += hi.f;
        }
        float rin = rsqrtf((float)(ind < 1 ? 1 : ind));
        tot.x += rin * acc.x;
        tot.y += rin * acc.y;
    }
    int c0 = ((2 * lane) & 7) * 16 + (lane >> 2);
    Z[(size_t)d * D + c0]      = tot.x;
    Z[(size_t)d * D + c0 + 16] = tot.y;
}

// ---------------------------------------------------------------------------
extern "C" void kernel_launch(void* const* d_in, const int* in_sizes, int n_in,
                              void* d_out, int out_size, void* d_ws, size_t ws_size,
                              hipStream_t stream) {
    const int*   edges = (const int*)d_in[0];
    const float* X     = (const float*)d_in[1];
    const float* W     = (const float*)d_in[2];
    float*       Z     = (float*)d_out;

    auto align256 = [](size_t x) { return (x + 255) & ~(size_t)255; };
    char* ws = (char*)d_ws;
    size_t off = 0;
    int* esrc          = (int*)(ws + off);            off = align256(off + (size_t)N_REL * N_NODES * MAXDEG * sizeof(int));
    unsigned short* Xb = (unsigned short*)(ws + off); off = align256(off + (size_t)M_PAD * D * sizeof(short));
    unsigned short* Wt = (unsigned short*)(ws + off); off = align256(off + (size_t)KTOT * D * sizeof(short));
    int* indeg         = (int*)(ws + off);            off = align256(off + (size_t)N_REL * N_NODES * sizeof(int));
    int* outdeg        = (int*)(ws + off);            off = align256(off + (size_t)N_REL * N_NODES * sizeof(int));
    int* gcur          = (int*)(ws + off);            off = align256(off + (size_t)2 * N_REL * NBKT * sizeof(int));
    unsigned short* Yb = (unsigned short*)(ws + off); off = align256(off + (size_t)M_PAD * KTOT * sizeof(short));

    // Partition buffers alias Ybig (consumed before gemm writes Ybig):
    uint2*    part_d = (uint2*)Yb;                                    // 58.7 MB
    unsigned* part_s = (unsigned*)((char*)Yb + (size_t)N_REL * NBKT * BCAP * sizeof(uint2));  // 29.4 MB
    int* gcur_d = gcur;
    int* gcur_s = gcur + N_REL * NBKT;

    hipMemsetAsync(gcur, 0, (size_t)2 * N_REL * NBKT * sizeof(int), stream);

    dim3 pgrid(64, N_REL);
    partition_dst<<<pgrid, 256, 0, stream>>>(edges, part_d, gcur_d);
    partition_src<<<pgrid, 256, 0, stream>>>(edges, part_s, gcur_s);

    dim3 bgrid(NBKT_REAL, N_REL);
    ell_build<<<bgrid, 256, 0, stream>>>(part_d, gcur_d, esrc, indeg);
    outdeg_hist<<<bgrid, 256, 0, stream>>>(part_s, gcur_s, outdeg);

    xcast_kernel<<<(N_NODES * D / 4 + 255) / 256, 256, 0, stream>>>(X, Xb);
    wcast_kernel<<<(N_REL * D * D + 255) / 256, 256, 0, stream>>>(W, Wt);

    dim3 ggrid(M_PAD / 128, N_REL);
    gemm_mfma<<<ggrid, 256, 0, stream>>>(Xb, Wt, outdeg, Yb);

    gather_ell<<<(N_NODES + 3) / 4, 256, 0, stream>>>(esrc, indeg, (const unsigned int*)Yb, Z);
}

// Round 6
// 577.403 us; speedup vs baseline: 1.2356x; 1.2356x over previous
//
#include <hip/hip_runtime.h>
#include <hip/hip_bf16.h>

constexpr int N_NODES = 100000;
constexpr int N_REL   = 4;
constexpr int N_EDGES = 600000;
constexpr int MAXDEG  = 32;          // Poisson(6): P(deg>=32) ~ 7e-14 per node
constexpr int D       = 128;
constexpr int KTOT    = N_REL * D;   // 512 concat cols of A
constexpr int M_PAD   = 100096;      // 782 blocks * 128 rows

constexpr int BLD_BLKS = (N_REL * N_EDGES) / 256;   // 9375
constexpr int XC_BLKS  = (N_NODES * D / 4) / 256;   // 12500
constexpr int WC_BLKS  = (N_REL * D * D) / 256;     // 256

typedef __attribute__((ext_vector_type(8))) short bf16x8;   // MFMA A/B frag (4 VGPRs)
typedef __attribute__((ext_vector_type(4))) float f32x4;    // MFMA C/D frag

static __device__ __forceinline__ unsigned short f2bf(float f) {
    union { float f; unsigned int u; } v; v.f = f;
    unsigned int r = (v.u + 0x7fffu + ((v.u >> 16) & 1u)) >> 16;  // RNE
    return (unsigned short)r;
}

// ---------------------------------------------------------------------------
// 1) Fused build + casts. Build blocks are txn-bound (VALUBusy<1%, HBM 12%),
//    so the cast blocks' streaming traffic rides in the idle bandwidth.
//    blocks [0, BLD):          degree count + ELL fill (3 scattered txns/edge)
//    blocks [BLD, BLD+XC):     X -> bf16 cast
//    blocks [BLD+XC, ..+WC):   W cast+transpose -> Wt[n][r*128+k]
// ---------------------------------------------------------------------------
__global__ __launch_bounds__(256) void build_fused(const int* __restrict__ edges,
                                                   int* __restrict__ outdeg,
                                                   int* __restrict__ cursor,
                                                   int* __restrict__ esrc,
                                                   const float* __restrict__ X,
                                                   unsigned short* __restrict__ Xb,
                                                   const float* __restrict__ W,
                                                   unsigned short* __restrict__ Wt) {
    int b = blockIdx.x;
    if (b < BLD_BLKS) {
        int t = b * 256 + threadIdx.x;
        int r = t / N_EDGES;
        int e = t - r * N_EDGES;
        int s = edges[(size_t)r * 2 * N_EDGES + e];
        int d = edges[(size_t)r * 2 * N_EDGES + N_EDGES + e];
        atomicAdd(&outdeg[r * N_NODES + s], 1);
        int pos = atomicAdd(&cursor[r * N_NODES + d], 1);
        if (pos < MAXDEG)
            esrc[((size_t)r * N_NODES + d) * MAXDEG + pos] = s;
    } else if (b < BLD_BLKS + XC_BLKS) {
        int t = (b - BLD_BLKS) * 256 + threadIdx.x;
        float4 v = ((const float4*)X)[t];
        union { unsigned short u[4]; uint2 d; } o;
        o.u[0] = f2bf(v.x); o.u[1] = f2bf(v.y); o.u[2] = f2bf(v.z); o.u[3] = f2bf(v.w);
        ((uint2*)Xb)[t] = o.d;
    } else {
        int t = (b - BLD_BLKS - XC_BLKS) * 256 + threadIdx.x;
        int r = t >> 14;
        int k = (t >> 7) & 127;
        int n = t & 127;
        Wt[(size_t)n * KTOT + r * D + k] = f2bf(W[t]);
    }
}

// ---------------------------------------------------------------------------
// 2) Fused 4-relation gather: one wave per dst node. The 4 relations' edge
//    loops are interleaved -> 4 independent in-flight loads (MLP), and the
//    random-read working set is Xb (25.6 MB), not a 102 MB Y buffer.
//    A[d][r*128+c] = bf16( rin_r[d] * sum_e rout_r[src_e] * Xb[src_e][c] )
// ---------------------------------------------------------------------------
__global__ __launch_bounds__(256) void gather_ell(const int* __restrict__ esrc,
                                                  const int* __restrict__ cursor,
                                                  const int* __restrict__ outdeg,
                                                  const unsigned int* __restrict__ Xb2,
                                                  unsigned int* __restrict__ A4) {
    int w    = threadIdx.x >> 6;
    int lane = threadIdx.x & 63;
    int d    = blockIdx.x * 4 + w;
    if (d >= N_NODES) return;

    int   n[N_REL];
    float rin[N_REL];
    int   s_l[N_REL];
    float c_l[N_REL];
#pragma unroll
    for (int r = 0; r < N_REL; r++) {
        int ind = cursor[r * N_NODES + d];
        n[r]   = ind > MAXDEG ? MAXDEG : ind;
        rin[r] = rsqrtf((float)(ind < 1 ? 1 : ind));
        s_l[r] = 0;
        c_l[r] = 0.f;
        if (lane < n[r]) {
            s_l[r] = esrc[((size_t)r * N_NODES + d) * MAXDEG + lane];
            int od = outdeg[r * N_NODES + s_l[r]];
            c_l[r] = rsqrtf((float)(od < 1 ? 1 : od));
        }
    }
    int nmax = max(max(n[0], n[1]), max(n[2], n[3]));

    float2 acc[N_REL];
#pragma unroll
    for (int r = 0; r < N_REL; r++) acc[r] = make_float2(0.f, 0.f);

    for (int i = 0; i < nmax; i++) {
        unsigned v[N_REL];
        float    c[N_REL];
        // issue all active loads first (independent -> overlapped)
#pragma unroll
        for (int r = 0; r < N_REL; r++) {
            int s = __shfl(s_l[r], i);      // lanes >= n[r] hold 0 -> valid addr
            c[r]  = __shfl(c_l[r], i);      // 0 when inactive
            v[r]  = 0u;
            if (i < n[r])                   // wave-uniform branch
                v[r] = Xb2[(size_t)s * (D / 2) + lane];
        }
#pragma unroll
        for (int r = 0; r < N_REL; r++) {
            union { unsigned u; float f; } lo, hi;
            lo.u = v[r] << 16;
            hi.u = v[r] & 0xFFFF0000u;
            acc[r].x += c[r] * lo.f;
            acc[r].y += c[r] * hi.f;
        }
    }

#pragma unroll
    for (int r = 0; r < N_REL; r++) {
        unsigned lo = f2bf(rin[r] * acc[r].x);
        unsigned hi = f2bf(rin[r] * acc[r].y);
        A4[(size_t)d * (KTOT / 2) + r * (D / 2) + lane] = lo | (hi << 16);
    }
}

// ---------------------------------------------------------------------------
// 3) Final GEMM: Z[100K][128] = A[100K][512](bf16) @ Wt^T  via 16x16x32 MFMA.
//    A streamed linearly (latency-tolerant), Wt 128KB L2-hot. No LDS.
// ---------------------------------------------------------------------------
__global__ __launch_bounds__(256) void gemm_mfma(const unsigned short* __restrict__ A,
                                                 const unsigned short* __restrict__ Wt,
                                                 float* __restrict__ Z) {
    int w    = threadIdx.x >> 6;
    int lane = threadIdx.x & 63;
    int l15  = lane & 15;
    int quad = lane >> 4;
    int row0 = blockIdx.x * 128 + w * 32;

    f32x4 acc[2][8];
#pragma unroll
    for (int m = 0; m < 2; m++)
#pragma unroll
        for (int j = 0; j < 8; j++) acc[m][j] = (f32x4){0.f, 0.f, 0.f, 0.f};

    for (int k0 = 0; k0 < KTOT; k0 += 32) {
        bf16x8 a[2];
#pragma unroll
        for (int m = 0; m < 2; m++)
            a[m] = *(const bf16x8*)(A + (size_t)(row0 + m * 16 + l15) * KTOT + k0 + quad * 8);
#pragma unroll
        for (int j = 0; j < 8; j++) {
            bf16x8 b = *(const bf16x8*)(Wt + (size_t)(j * 16 + l15) * KTOT + k0 + quad * 8);
            acc[0][j] = __builtin_amdgcn_mfma_f32_16x16x32_bf16(a[0], b, acc[0][j], 0, 0, 0);
            acc[1][j] = __builtin_amdgcn_mfma_f32_16x16x32_bf16(a[1], b, acc[1][j], 0, 0, 0);
        }
    }

    // C/D layout: col = lane&15, row = quad*4 + reg
#pragma unroll
    for (int m = 0; m < 2; m++)
#pragma unroll
        for (int reg = 0; reg < 4; reg++) {
            int row = row0 + m * 16 + quad * 4 + reg;
            if (row < N_NODES) {
#pragma unroll
                for (int j = 0; j < 8; j++)
                    Z[(size_t)row * D + j * 16 + l15] = acc[m][j][reg];
            }
        }
}

// ---------------------------------------------------------------------------
extern "C" void kernel_launch(void* const* d_in, const int* in_sizes, int n_in,
                              void* d_out, int out_size, void* d_ws, size_t ws_size,
                              hipStream_t stream) {
    const int*   edges = (const int*)d_in[0];
    const float* X     = (const float*)d_in[1];
    const float* W     = (const float*)d_in[2];
    float*       Z     = (float*)d_out;

    auto align256 = [](size_t x) { return (x + 255) & ~(size_t)255; };
    char* ws = (char*)d_ws;
    size_t off = 0;
    int* outdeg        = (int*)(ws + off);            off = align256(off + (size_t)N_REL * N_NODES * sizeof(int));
    int* cursor        = (int*)(ws + off);            off = align256(off + (size_t)N_REL * N_NODES * sizeof(int));
    int* esrc          = (int*)(ws + off);            off = align256(off + (size_t)N_REL * N_NODES * MAXDEG * sizeof(int));
    unsigned short* Xb = (unsigned short*)(ws + off); off = align256(off + (size_t)N_NODES * D * sizeof(short));
    unsigned short* Wt = (unsigned short*)(ws + off); off = align256(off + (size_t)KTOT * D * sizeof(short));
    unsigned short* A  = (unsigned short*)(ws + off); off = align256(off + (size_t)M_PAD * KTOT * sizeof(short));

    // zero the two adjacent counter arrays with one memset (ws poisoned every call)
    hipMemsetAsync(outdeg, 0, (size_t)2 * N_REL * N_NODES * sizeof(int), stream);

    build_fused<<<BLD_BLKS + XC_BLKS + WC_BLKS, 256, 0, stream>>>(
        edges, outdeg, cursor, esrc, X, Xb, W, Wt);

    gather_ell<<<(N_NODES + 3) / 4, 256, 0, stream>>>(
        esrc, cursor, outdeg, (const unsigned int*)Xb, (unsigned int*)A);

    gemm_mfma<<<M_PAD / 128, 256, 0, stream>>>(A, Wt, Z);
}